// Round 8
// baseline (17.149 us; speedup 1.0000x reference)
//
#include <hip/hip_runtime.h>
#include <math.h>

#define BATCH  8
#define NPRED  4096
#define MGT    2048
#define UU     4096
#define SPB    8                     // pred-slice blocks per batch
#define NSLOT  (BATCH * SPB)         // 64 producer blocks / handshake slots
#define PSLICE (NPRED / SPB)         // 512 preds per block
#define GPT    (MGT / 256)           // 8 gt boxes per thread (all gts of the batch)
#define MAGIC  0xC0FFEE00u
#define SLOT_STRIDE 16               // 16 x u64 = 128 B: one cache line per slot

__global__ __launch_bounds__(256) void fused_kernel(
    const float4* __restrict__ pred_boxes,     // [B*N]
    const int2*   __restrict__ pred_classes2,  // [B*N/2]
    const float4* __restrict__ gt_boxes,       // [B*M]
    const float4* __restrict__ union_scores4,  // [U/4]
    const int4*   __restrict__ union_classes4, // [U/4]
    unsigned long long* __restrict__ slots,    // ws: NSLOT lines, 128 B apart
    float* __restrict__ out)                   // [2] = {max_prob_t, max_iou_t}
{
    const int tid = threadIdx.x;
    const int blk = blockIdx.x;

    if (blk < NSLOT) {
        // ---------- producer: (batch b, pred slice psub) vs ALL gts of b ----------
        __shared__ float4 plist[PSLICE];     // worst-case all-person slice
        __shared__ float  parea[PSLICE];
        __shared__ int    lcount;
        __shared__ float  wmax[4];

        const int b    = blk >> 3;
        const int psub = blk & 7;

        // ---- issue ALL loads up front (11 independent vmem ops, one latency hop) ----
        const int  cbase = b * (NPRED / 2) + psub * (PSLICE / 2) + tid;  // int2 idx
        const int2 cl    = pred_classes2[cbase];
        const int  pb    = cbase * 2;                                    // float4 idx
        const float4 bx0 = pred_boxes[pb + 0];
        const float4 bx1 = pred_boxes[pb + 1];

        float4 g[GPT];
        #pragma unroll
        for (int k = 0; k < GPT; ++k)
            g[k] = gt_boxes[b * MGT + k * 256 + tid];

        float ga[GPT];
        #pragma unroll
        for (int k = 0; k < GPT; ++k)
            ga[k] = (g[k].z - g[k].x) * (g[k].w - g[k].y);  // zeroed invalid gt -> iou 0

        if (tid == 0) lcount = 0;
        __syncthreads();

        // ---- compact person preds (boxes already in registers) ----
        if (cl.x == 0) { int p = atomicAdd(&lcount, 1); plist[p] = bx0; parea[p] = (bx0.z - bx0.x) * (bx0.w - bx0.y); }
        if (cl.y == 0) { int p = atomicAdd(&lcount, 1); plist[p] = bx1; parea[p] = (bx1.z - bx1.x) * (bx1.w - bx1.y); }
        __syncthreads();

        // ---- IoU: this thread's 8 gts vs the ~6 compacted persons ----
        const int cnt = lcount;              // uniform -> LDS broadcast reads
        float best[GPT];
        #pragma unroll
        for (int k = 0; k < GPT; ++k) best[k] = 0.0f;

        for (int j = 0; j < cnt; ++j) {
            const float4 p  = plist[j];
            const float  ap = parea[j];
            #pragma unroll
            for (int k = 0; k < GPT; ++k) {
                float iw = fminf(p.z, g[k].z) - fmaxf(p.x, g[k].x);
                float ih = fminf(p.w, g[k].w) - fmaxf(p.y, g[k].y);
                iw = fmaxf(iw, 0.0f); ih = fmaxf(ih, 0.0f);
                const float inter = iw * ih;
                const float uni   = ap + ga[k] - inter;
                best[k] = fmaxf(best[k], inter * __builtin_amdgcn_rcpf(fmaxf(uni, 1e-9f)));
            }
        }

        float bestv = best[0];
        #pragma unroll
        for (int k = 1; k < GPT; ++k) bestv = fmaxf(bestv, best[k]);

        // block max reduce
        #pragma unroll
        for (int off = 32; off >= 1; off >>= 1)
            bestv = fmaxf(bestv, __shfl_xor(bestv, off));
        if ((tid & 63) == 0) wmax[tid >> 6] = bestv;
        __syncthreads();
        if (tid == 0) {
            const float m = fmaxf(fmaxf(wmax[0], wmax[1]), fmaxf(wmax[2], wmax[3]));
            // iou >= 0 -> raw float bits are uint-monotone; exact payload
            const unsigned long long v =
                ((unsigned long long)MAGIC << 32) | (unsigned long long)__float_as_uint(m);
            __hip_atomic_store(&slots[blk * SLOT_STRIDE], v,
                               __ATOMIC_RELAXED, __HIP_MEMORY_SCOPE_AGENT);
        }
    } else {
        // ---------- finalizer: union masked max (overlaps producers), then collect ----------
        __shared__ float pmax[4];
        float mp = -INFINITY;
        #pragma unroll
        for (int s = 0; s < UU / (256 * 4); ++s) {          // 4 sub-steps
            const int i = s * 256 + tid;
            const int4   c = union_classes4[i];
            const float4 v = union_scores4[i];
            if (c.x == 0) mp = fmaxf(mp, v.x);
            if (c.y == 0) mp = fmaxf(mp, v.y);
            if (c.z == 0) mp = fmaxf(mp, v.z);
            if (c.w == 0) mp = fmaxf(mp, v.w);
        }
        #pragma unroll
        for (int off = 32; off >= 1; off >>= 1)
            mp = fmaxf(mp, __shfl_xor(mp, off));
        if ((tid & 63) == 0) pmax[tid >> 6] = mp;
        __syncthreads();
        if (tid == 0)
            out[0] = fmaxf(fmaxf(pmax[0], pmax[1]), fmaxf(pmax[2], pmax[3]));

        // wave 0: lane l polls its own 128B-padded slot (1 writer + 1 reader per line)
        if (tid < 64) {
            unsigned long long v;
            do {
                v = __hip_atomic_load(&slots[tid * SLOT_STRIDE],
                                      __ATOMIC_RELAXED, __HIP_MEMORY_SCOPE_AGENT);
            } while ((unsigned int)(v >> 32) != MAGIC);
            // reset so the next replay starts from a non-magic state
            __hip_atomic_store(&slots[tid * SLOT_STRIDE], 0ULL,
                               __ATOMIC_RELAXED, __HIP_MEMORY_SCOPE_AGENT);

            unsigned int q = (unsigned int)v;               // raw float bits, iou >= 0
            // max over the 8 pred-slices of each batch (lanes 8b..8b+7)
            q = max(q, (unsigned int)__shfl_xor((int)q, 1, 8));
            q = max(q, (unsigned int)__shfl_xor((int)q, 2, 8));
            q = max(q, (unsigned int)__shfl_xor((int)q, 4, 8));
            // fixed-order sum over the 8 batch maxima -> bitwise deterministic
            float s = 0.0f;
            #pragma unroll
            for (int i = 0; i < 8; ++i)
                s += __uint_as_float((unsigned int)__shfl((int)q, 8 * i, 64));
            if (tid == 0)
                out[1] = s * 0.125f;                        // mean over batches
        }
    }
}

extern "C" void kernel_launch(void* const* d_in, const int* in_sizes, int n_in,
                              void* d_out, int out_size, void* d_ws, size_t ws_size,
                              hipStream_t stream) {
    const float4* pred_boxes    = (const float4*)d_in[0];
    // d_in[1] = pred_scores (unused by the reference result)
    const int2*   pred_classes2 = (const int2*)d_in[2];
    const float4* gt_boxes      = (const float4*)d_in[3];
    const float4* union_scores4 = (const float4*)d_in[4];
    const int4*   union_classes4= (const int4*)d_in[5];
    float* out = (float*)d_out;
    unsigned long long* slots = (unsigned long long*)d_ws;  // 64 x 128 B lines

    fused_kernel<<<NSLOT + 1, 256, 0, stream>>>(pred_boxes, pred_classes2, gt_boxes,
                                                union_scores4, union_classes4, slots, out);
}

// Round 9
// 12.298 us; speedup vs baseline: 1.3944x; 1.3944x over previous
//
#include <hip/hip_runtime.h>
#include <math.h>

#define BATCH  8
#define NPRED  4096
#define MGT    2048
#define UU     4096
#define SPB    8                     // pred-slice blocks per batch
#define NPROD  (BATCH * SPB)         // 64 producer blocks
#define PSLICE (NPRED / SPB)         // 512 preds per block
#define GPT    (MGT / 256)           // 8 gt boxes per thread
#define MAGIC  0xC0FFEE00u
#define STRIDE 16                    // u64 stride -> 128 B per slot (own cache line)
// slots 0..63: per-producer IoU max; slot 64: union masked max. 65 x 128 B.

__device__ __forceinline__ void snapshot_finalize(
    unsigned long long* __restrict__ slots,
    float* __restrict__ out,
    int tid, int blk, unsigned long long myv)
{
    // Own tagged store is already issued by lane 0 of wave 0 (exec-masked in
    // this same wave). Drain it to the coherence point BEFORE snapshotting:
    // the last-committing block therefore sees all 65 tags -> >=1 completer.
    asm volatile("s_waitcnt vmcnt(0)" ::: "memory");

    if (tid >= 64) return;                        // wave 0 only
    const int lane = tid;

    // lane l reads producer slot l (own slot from register, not memory)
    unsigned long long v = (blk == lane)
        ? myv
        : __hip_atomic_load(&slots[lane * STRIDE], __ATOMIC_RELAXED, __HIP_MEMORY_SCOPE_AGENT);
    // lane 0 reads the union slot (or register if we ARE the union block)
    unsigned long long vu = myv;
    if (blk != NPROD && lane == 0)
        vu = __hip_atomic_load(&slots[NPROD * STRIDE], __ATOMIC_RELAXED, __HIP_MEMORY_SCOPE_AGENT);

    const int ok64 = __all((unsigned int)(v >> 32) == MAGIC);
    const int okU  = __shfl((int)((unsigned int)(vu >> 32) == MAGIC), 0);
    if (!(ok64 && okU)) return;                   // incomplete: a later block completes

    // complete snapshot: slots are write-once per replay -> values final
    const unsigned int ubits = (unsigned int)__shfl((int)(unsigned int)vu, 0);

    unsigned int q = (unsigned int)v;             // raw float bits, iou >= 0
    q = max(q, (unsigned int)__shfl_xor((int)q, 1, 8));
    q = max(q, (unsigned int)__shfl_xor((int)q, 2, 8));
    q = max(q, (unsigned int)__shfl_xor((int)q, 4, 8));
    float s = 0.0f;
    #pragma unroll
    for (int i = 0; i < 8; ++i)                   // fixed-order sum -> deterministic bits
        s += __uint_as_float((unsigned int)__shfl((int)q, 8 * i, 64));

    if (lane == 0) {
        out[0] = __uint_as_float(ubits);          // max_prob_t
        out[1] = s * 0.125f;                      // max_iou_t (mean over batches)
        __hip_atomic_store(&slots[NPROD * STRIDE], 0ULL, __ATOMIC_RELAXED, __HIP_MEMORY_SCOPE_AGENT);
    }
    // reset all producer slots so the next replay starts non-magic (idempotent)
    __hip_atomic_store(&slots[lane * STRIDE], 0ULL, __ATOMIC_RELAXED, __HIP_MEMORY_SCOPE_AGENT);
}

__global__ __launch_bounds__(256) void fused_kernel(
    const float4* __restrict__ pred_boxes,     // [B*N]
    const int2*   __restrict__ pred_classes2,  // [B*N/2]
    const float4* __restrict__ gt_boxes,       // [B*M]
    const float4* __restrict__ union_scores4,  // [U/4]
    const int4*   __restrict__ union_classes4, // [U/4]
    unsigned long long* __restrict__ slots,    // ws: 65 slots, 128 B apart
    float* __restrict__ out)                   // [2] = {max_prob_t, max_iou_t}
{
    const int tid = threadIdx.x;
    const int blk = blockIdx.x;

    __shared__ float red[4];

    unsigned long long myv;

    if (blk < NPROD) {
        // ---------- producer: (batch b, pred slice psub) vs ALL gts of b ----------
        __shared__ float4 plist[PSLICE];     // worst-case all-person slice
        __shared__ float  parea[PSLICE];
        __shared__ int    lcount;

        const int b    = blk >> 3;
        const int psub = blk & 7;

        // ---- issue ALL loads up front (11 independent vmem ops, one latency hop) ----
        const int  cbase = b * (NPRED / 2) + psub * (PSLICE / 2) + tid;  // int2 idx
        const int2 cl    = pred_classes2[cbase];
        const float4 bx0 = pred_boxes[cbase * 2 + 0];
        const float4 bx1 = pred_boxes[cbase * 2 + 1];

        float4 g[GPT];
        #pragma unroll
        for (int k = 0; k < GPT; ++k)
            g[k] = gt_boxes[b * MGT + k * 256 + tid];

        float ga[GPT];
        #pragma unroll
        for (int k = 0; k < GPT; ++k)
            ga[k] = (g[k].z - g[k].x) * (g[k].w - g[k].y);  // zeroed invalid gt -> iou 0

        if (tid == 0) lcount = 0;
        __syncthreads();

        // ---- compact person preds (boxes already in registers) ----
        if (cl.x == 0) { int p = atomicAdd(&lcount, 1); plist[p] = bx0; parea[p] = (bx0.z - bx0.x) * (bx0.w - bx0.y); }
        if (cl.y == 0) { int p = atomicAdd(&lcount, 1); plist[p] = bx1; parea[p] = (bx1.z - bx1.x) * (bx1.w - bx1.y); }
        __syncthreads();

        // ---- IoU: this thread's 8 gts vs the ~6 compacted persons ----
        const int cnt = lcount;              // uniform -> LDS broadcast reads
        float best[GPT];
        #pragma unroll
        for (int k = 0; k < GPT; ++k) best[k] = 0.0f;

        for (int j = 0; j < cnt; ++j) {
            const float4 p  = plist[j];
            const float  ap = parea[j];
            #pragma unroll
            for (int k = 0; k < GPT; ++k) {
                float iw = fminf(p.z, g[k].z) - fmaxf(p.x, g[k].x);
                float ih = fminf(p.w, g[k].w) - fmaxf(p.y, g[k].y);
                iw = fmaxf(iw, 0.0f); ih = fmaxf(ih, 0.0f);
                const float inter = iw * ih;
                const float uni   = ap + ga[k] - inter;
                best[k] = fmaxf(best[k], inter * __builtin_amdgcn_rcpf(fmaxf(uni, 1e-9f)));
            }
        }

        float bestv = best[0];
        #pragma unroll
        for (int k = 1; k < GPT; ++k) bestv = fmaxf(bestv, best[k]);

        // block max reduce
        #pragma unroll
        for (int off = 32; off >= 1; off >>= 1)
            bestv = fmaxf(bestv, __shfl_xor(bestv, off));
        if ((tid & 63) == 0) red[tid >> 6] = bestv;
        __syncthreads();

        // all wave-0 lanes recompute the block max identically from LDS
        const float m = fmaxf(fmaxf(red[0], red[1]), fmaxf(red[2], red[3]));
        myv = ((unsigned long long)MAGIC << 32) | (unsigned long long)__float_as_uint(m);
        if (tid == 0)
            __hip_atomic_store(&slots[blk * STRIDE], myv,
                               __ATOMIC_RELAXED, __HIP_MEMORY_SCOPE_AGENT);
    } else {
        // ---------- union block: masked max over union entries ----------
        float mp = -INFINITY;
        #pragma unroll
        for (int s = 0; s < UU / (256 * 4); ++s) {          // 4 sub-steps
            const int i = s * 256 + tid;
            const int4   c = union_classes4[i];
            const float4 v = union_scores4[i];
            if (c.x == 0) mp = fmaxf(mp, v.x);
            if (c.y == 0) mp = fmaxf(mp, v.y);
            if (c.z == 0) mp = fmaxf(mp, v.z);
            if (c.w == 0) mp = fmaxf(mp, v.w);
        }
        #pragma unroll
        for (int off = 32; off >= 1; off >>= 1)
            mp = fmaxf(mp, __shfl_xor(mp, off));
        if ((tid & 63) == 0) red[tid >> 6] = mp;
        __syncthreads();

        const float m = fmaxf(fmaxf(red[0], red[1]), fmaxf(red[2], red[3]));
        myv = ((unsigned long long)MAGIC << 32) | (unsigned long long)__float_as_uint(m);
        if (tid == 0)
            __hip_atomic_store(&slots[NPROD * STRIDE], myv,
                               __ATOMIC_RELAXED, __HIP_MEMORY_SCOPE_AGENT);
    }

    // ---------- bounded, spin-free completion election (all 65 blocks) ----------
    snapshot_finalize(slots, out, tid, blk, myv);
}

extern "C" void kernel_launch(void* const* d_in, const int* in_sizes, int n_in,
                              void* d_out, int out_size, void* d_ws, size_t ws_size,
                              hipStream_t stream) {
    const float4* pred_boxes    = (const float4*)d_in[0];
    // d_in[1] = pred_scores (unused by the reference result)
    const int2*   pred_classes2 = (const int2*)d_in[2];
    const float4* gt_boxes      = (const float4*)d_in[3];
    const float4* union_scores4 = (const float4*)d_in[4];
    const int4*   union_classes4= (const int4*)d_in[5];
    float* out = (float*)d_out;
    unsigned long long* slots = (unsigned long long*)d_ws;  // 65 x 128 B lines

    fused_kernel<<<NPROD + 1, 256, 0, stream>>>(pred_boxes, pred_classes2, gt_boxes,
                                                union_scores4, union_classes4, slots, out);
}